// Round 10
// baseline (316.416 us; speedup 1.0000x reference)
//
#include <hip/hip_runtime.h>
#include <math.h>

typedef __attribute__((ext_vector_type(8))) short bf16x8;
typedef __attribute__((ext_vector_type(4))) short short4v;
typedef __attribute__((ext_vector_type(4))) float f32x4;

#define WFRAG (16 * 4 * 64 * 8)

// ---------------- helpers ----------------

__device__ inline int detect_is64(const int* __restrict__ ei) {
    int is64 = 1;
#pragma unroll
    for (int k = 1; k < 16; k += 2) is64 &= (ei[k] == 0);
    return is64;
}

__device__ inline void split1(float f, short& hi, short& lo) {
    unsigned u = __float_as_uint(f);
    hi = (short)(u >> 16);
    float fl = f - __uint_as_float(u & 0xffff0000u);
    lo = (short)(__float_as_uint(fl) >> 16);
}

__device__ inline void cvt8(const float4& a, const float4& b, bf16x8& hi, bf16x8& lo) {
    float f[8] = {a.x, a.y, a.z, a.w, b.x, b.y, b.z, b.w};
#pragma unroll
    for (int j = 0; j < 8; j++) {
        unsigned u = __float_as_uint(f[j]);
        hi[j] = (short)(u >> 16);
        float fl = f[j] - __uint_as_float(u & 0xffff0000u);
        lo[j] = (short)(__float_as_uint(fl) >> 16);
    }
}

// ---------------- prologue: prep_w (blocks 0..111) + cvt_x + degree count ----------------

__global__ __launch_bounds__(256) void prologue(const float* __restrict__ Wl,
                                                const float* __restrict__ Wr,
                                                short* __restrict__ Whi,
                                                short* __restrict__ Wlo,
                                                const float4* __restrict__ x4,
                                                short* __restrict__ cvH,
                                                short* __restrict__ cvL,
                                                const int* __restrict__ ei,
                                                int* __restrict__ deg,
                                                int N, int E) {
    __shared__ float Wt[128][17];
    int b = blockIdx.x, t = threadIdx.x;
    if (b < 112) {
        int l = b >> 4;
        int tile = b & 15;
        int c0 = tile * 16;
        const float* Wsrc = (c0 < 128) ? Wl + (size_t)l * 16384 : Wr + (size_t)l * 16384;
        int cbase = (c0 < 128) ? c0 : c0 - 128;
#pragma unroll
        for (int it = 0; it < 8; it++) {
            int idx = it * 256 + t;
            int k = idx >> 4, c = idx & 15;
            Wt[k][c] = Wsrc[(size_t)k * 128 + cbase + c];
        }
        __syncthreads();
        int kt = t >> 6, lane = t & 63, q = (lane >> 4), cl = lane & 15;
        bf16x8 hi, lo;
#pragma unroll
        for (int j = 0; j < 8; j++) {
            short h, lw;
            split1(Wt[kt * 32 + q * 8 + j][cl], h, lw);
            hi[j] = h; lo[j] = lw;
        }
        size_t off = ((((size_t)l * 16 + tile) * 4 + kt) * 64 + lane) * 8;
        *(bf16x8*)(Whi + off) = hi;
        *(bf16x8*)(Wlo + off) = lo;
        return;
    }
    int rb = b - 112;
    int RB = gridDim.x - 112;
    int n8 = N * 16;
    for (int id = rb * 256 + t; id < n8; id += RB * 256) {
        float4 a = x4[2 * id];
        float4 bb = x4[2 * id + 1];
        bf16x8 h, lw;
        cvt8(a, bb, h, lw);
        *(bf16x8*)(cvH + (size_t)id * 8) = h;
        *(bf16x8*)(cvL + (size_t)id * 8) = lw;
    }
    int is64 = detect_is64(ei);
    for (int e = rb * 256 + t; e < E; e += RB * 256) {
        long long pos = (long long)E + e;
        int d = ei[is64 ? 2 * pos : pos];
        if ((unsigned)d < (unsigned)N) atomicAdd(&deg[d], 1);
    }
}

// ---------------- scan (block 0) + layer-0 GEMM (blocks 1..) in ONE dispatch ----------------

__global__ __launch_bounds__(512, 1) void scan_gemm0(const int* __restrict__ deg,
                                                     int* __restrict__ offp,
                                                     int* __restrict__ cur, int N,
                                                     const short* __restrict__ xhi,
                                                     const short* __restrict__ xlo,
                                                     const short* __restrict__ WhiL,
                                                     const short* __restrict__ WloL,
                                                     const float* __restrict__ blv,
                                                     const float* __restrict__ brv,
                                                     float* __restrict__ xl,
                                                     float* __restrict__ xr,
                                                     int ntiles) {
    __shared__ int wsum[8];
    int t = threadIdx.x;
    if (blockIdx.x == 0) {
        int per = (N + 511) >> 9;
        int b0 = t * per;
        int s = 0;
        for (int k = 0; k < per; k++) {
            int idx = b0 + k;
            if (idx < N) s += deg[idx];
        }
        int lane = t & 63, w = t >> 6;
        int v = s;
#pragma unroll
        for (int o = 1; o < 64; o <<= 1) {
            int u = __shfl_up(v, o, 64);
            if (lane >= o) v += u;
        }
        if (lane == 63) wsum[w] = v;
        __syncthreads();
        if (t == 0) {
            int r = 0;
#pragma unroll
            for (int j = 0; j < 8; j++) { int xx = wsum[j]; wsum[j] = r; r += xx; }
            offp[N] = r;
        }
        __syncthreads();
        int run = v - s + wsum[w];
        for (int k = 0; k < per; k++) {
            int idx = b0 + k;
            if (idx < N) {
                offp[idx] = run;
                cur[idx] = run;
                run += deg[idx];
            }
        }
        return;
    }

    int w = t >> 6, lane = t & 63, q = lane >> 4, cl = lane & 15;

    bf16x8 Bh[2][4], Bl[2][4];
    float biasv[2];
    float* op[2];
    int colc[2];
#pragma unroll
    for (int nt = 0; nt < 2; nt++) {
        int tile = w * 2 + nt;
        int col = tile * 16 + cl;
        if (col < 128) { biasv[nt] = blv[col]; op[nt] = xl; colc[nt] = col; }
        else           { biasv[nt] = brv[col - 128]; op[nt] = xr; colc[nt] = col - 128; }
#pragma unroll
        for (int kt = 0; kt < 4; kt++) {
            size_t o = (((size_t)tile * 4 + kt) * 64 + lane) * 8;
            Bh[nt][kt] = *(const bf16x8*)(WhiL + o);
            Bl[nt][kt] = *(const bf16x8*)(WloL + o);
        }
    }

    for (int rt = blockIdx.x - 1; rt < ntiles; rt += gridDim.x - 1) {
        int row = rt * 16 + cl;
        if (row >= N) row = N - 1;
        const short* ph = xhi + (size_t)row * 128 + q * 8;
        const short* pl = xlo + (size_t)row * 128 + q * 8;
        bf16x8 AH[4], AL[4];
#pragma unroll
        for (int kt = 0; kt < 4; kt++) {
            AH[kt] = *(const bf16x8*)(ph + kt * 32);
            AL[kt] = *(const bf16x8*)(pl + kt * 32);
        }

        f32x4 acc0 = {0.f, 0.f, 0.f, 0.f}, acc1 = {0.f, 0.f, 0.f, 0.f};
#pragma unroll
        for (int kt = 0; kt < 4; kt++) {
            acc0 = __builtin_amdgcn_mfma_f32_16x16x32_bf16(AH[kt], Bh[0][kt], acc0, 0, 0, 0);
            acc1 = __builtin_amdgcn_mfma_f32_16x16x32_bf16(AH[kt], Bh[1][kt], acc1, 0, 0, 0);
            acc0 = __builtin_amdgcn_mfma_f32_16x16x32_bf16(AL[kt], Bh[0][kt], acc0, 0, 0, 0);
            acc1 = __builtin_amdgcn_mfma_f32_16x16x32_bf16(AL[kt], Bh[1][kt], acc1, 0, 0, 0);
            acc0 = __builtin_amdgcn_mfma_f32_16x16x32_bf16(AH[kt], Bl[0][kt], acc0, 0, 0, 0);
            acc1 = __builtin_amdgcn_mfma_f32_16x16x32_bf16(AH[kt], Bl[1][kt], acc1, 0, 0, 0);
        }

        // C/D layout: col = lane&15, row = quad*4 + reg  [m89-verified]
#pragma unroll
        for (int nt = 0; nt < 2; nt++) {
            f32x4 a = nt ? acc1 : acc0;
#pragma unroll
            for (int r = 0; r < 4; r++) {
                int orow = rt * 16 + q * 4 + r;
                if (orow < N) op[nt][(size_t)orow * 128 + colc[nt]] = a[r] + biasv[nt];
            }
        }
    }
}

// ---------------- standalone GEMM (layers 1..6): A from agg's split-bf16 output ----------------

__global__ __launch_bounds__(512, 1) void gemm_x(const short* __restrict__ xhi,
                                                 const short* __restrict__ xlo,
                                                 const short* __restrict__ WhiL,
                                                 const short* __restrict__ WloL,
                                                 const float* __restrict__ blv,
                                                 const float* __restrict__ brv,
                                                 float* __restrict__ xl,
                                                 float* __restrict__ xr,
                                                 int N, int ntiles) {
    int t = threadIdx.x;
    int w = t >> 6, lane = t & 63, q = lane >> 4, cl = lane & 15;

    bf16x8 Bh[2][4], Bl[2][4];
    float biasv[2];
    float* op[2];
    int colc[2];
#pragma unroll
    for (int nt = 0; nt < 2; nt++) {
        int tile = w * 2 + nt;
        int col = tile * 16 + cl;
        if (col < 128) { biasv[nt] = blv[col]; op[nt] = xl; colc[nt] = col; }
        else           { biasv[nt] = brv[col - 128]; op[nt] = xr; colc[nt] = col - 128; }
#pragma unroll
        for (int kt = 0; kt < 4; kt++) {
            size_t o = (((size_t)tile * 4 + kt) * 64 + lane) * 8;
            Bh[nt][kt] = *(const bf16x8*)(WhiL + o);
            Bl[nt][kt] = *(const bf16x8*)(WloL + o);
        }
    }

    for (int rt = blockIdx.x; rt < ntiles; rt += gridDim.x) {
        int row = rt * 16 + cl;
        if (row >= N) row = N - 1;
        const short* ph = xhi + (size_t)row * 128 + q * 8;
        const short* pl = xlo + (size_t)row * 128 + q * 8;
        bf16x8 AH[4], AL[4];
#pragma unroll
        for (int kt = 0; kt < 4; kt++) {
            AH[kt] = *(const bf16x8*)(ph + kt * 32);
            AL[kt] = *(const bf16x8*)(pl + kt * 32);
        }

        f32x4 acc0 = {0.f, 0.f, 0.f, 0.f}, acc1 = {0.f, 0.f, 0.f, 0.f};
#pragma unroll
        for (int kt = 0; kt < 4; kt++) {
            acc0 = __builtin_amdgcn_mfma_f32_16x16x32_bf16(AH[kt], Bh[0][kt], acc0, 0, 0, 0);
            acc1 = __builtin_amdgcn_mfma_f32_16x16x32_bf16(AH[kt], Bh[1][kt], acc1, 0, 0, 0);
            acc0 = __builtin_amdgcn_mfma_f32_16x16x32_bf16(AL[kt], Bh[0][kt], acc0, 0, 0, 0);
            acc1 = __builtin_amdgcn_mfma_f32_16x16x32_bf16(AL[kt], Bh[1][kt], acc1, 0, 0, 0);
            acc0 = __builtin_amdgcn_mfma_f32_16x16x32_bf16(AH[kt], Bl[0][kt], acc0, 0, 0, 0);
            acc1 = __builtin_amdgcn_mfma_f32_16x16x32_bf16(AH[kt], Bl[1][kt], acc1, 0, 0, 0);
        }

#pragma unroll
        for (int nt = 0; nt < 2; nt++) {
            f32x4 a = nt ? acc1 : acc0;
#pragma unroll
            for (int r = 0; r < 4; r++) {
                int orow = rt * 16 + q * 4 + r;
                if (orow < N) op[nt][(size_t)orow * 128 + colc[nt]] = a[r] + biasv[nt];
            }
        }
    }
}

__global__ void fill_kernel(const int* __restrict__ ei, int E, int N,
                            int* __restrict__ cur, int* __restrict__ esrc) {
    int e = blockIdx.x * blockDim.x + threadIdx.x;
    if (e >= E) return;
    int is64 = detect_is64(ei);
    long long spos = e, dpos = (long long)E + e;
    int s = ei[is64 ? 2 * spos : spos];
    int d = ei[is64 ? 2 * dpos : dpos];
    if ((unsigned)d >= (unsigned)N || (unsigned)s >= (unsigned)N) return;
    int p = atomicAdd(&cur[d], 1);
    esrc[p] = s;
}

// ---------------- agg v4: HEAD-SLICED, L2-resident gather ----------------
// GATv2 is per-head separable. Block = (16 nodes) x (1 head); head = blockIdx & 7
// so each XCD's blocks touch only one head's 64-B line per node -> per-XCD L2
// footprint ~1 MB (fits 4 MB) instead of 5 MB thrash.
// 16 lanes per node-head: 4 edge-slots (s) x 4 feature-lanes (fl, one float4 each).
// Index depth-3 / data depth-2 pipeline as R9.

__global__ __launch_bounds__(256, 4) void agg_sliced(const float4* __restrict__ xl4,
                                                     const float4* __restrict__ xr4,
                                                     const int* __restrict__ off,
                                                     const int* __restrict__ esrc,
                                                     const float4* __restrict__ att4,
                                                     const float4* __restrict__ bias4,
                                                     short* __restrict__ nhi,
                                                     short* __restrict__ nlo,
                                                     float4* __restrict__ out4,
                                                     int N) {
    int t = threadIdx.x;
    int grp = t >> 4;                  // node slot in block: 0..15
    int u = t & 15, s = u >> 2, fl = u & 3;
    int h = blockIdx.x & 7;            // head -> XCD alignment
    int i = (blockIdx.x >> 3) * 16 + grp;
    if (i >= N) return;
    int fidx = h * 4 + fl;             // float4 index within a row (32 per row)

    float4 xr = xr4[(size_t)i * 32 + fidx];
    float4 at = att4[fidx];

    int start = off[i];
    int total = off[i + 1] - start + 1;   // + self-loop at slot 0
    int groups = (total + 3) >> 2;

    int k0 = s;
    int s0 = (k0 < total) ? ((k0 == 0) ? i : esrc[start + k0 - 1]) : i;
    float4 a = xl4[(size_t)s0 * 32 + fidx];
    int k1 = 4 + s;
    int s1 = (k1 < total) ? esrc[start + k1 - 1] : i;
    float4 b = xl4[(size_t)s1 * 32 + fidx];
    int k2 = 8 + s;
    int s2 = (k2 < total) ? esrc[start + k2 - 1] : i;

    float denom = 0.f;
    float4 ac = make_float4(0.f, 0.f, 0.f, 0.f);

    for (int g = 0; g < groups; g++) {
        float4 c = xl4[(size_t)s2 * 32 + fidx];
        int k3 = (g + 3) * 4 + s;
        int s3 = (k3 < total) ? esrc[start + k3 - 1] : i;

        int valid = (g * 4 + s) < total;
        float z0 = a.x + xr.x; z0 = (z0 > 0.f) ? z0 : 0.2f * z0;
        float z1 = a.y + xr.y; z1 = (z1 > 0.f) ? z1 : 0.2f * z1;
        float z2 = a.z + xr.z; z2 = (z2 > 0.f) ? z2 : 0.2f * z2;
        float z3 = a.w + xr.w; z3 = (z3 > 0.f) ? z3 : 0.2f * z3;
        float p = z0 * at.x + z1 * at.y + z2 * at.z + z3 * at.w;
        p += __shfl_xor(p, 1, 64);     // reduce over the 4 feature-lanes
        p += __shfl_xor(p, 2, 64);
        p = fminf(fmaxf(p, -80.f), 80.f);
        float wgt = valid ? __expf(p) : 0.f;
        denom += wgt;
        ac.x += wgt * a.x; ac.y += wgt * a.y; ac.z += wgt * a.z; ac.w += wgt * a.w;

        a = b; b = c; s2 = s3;
    }

    // reduce over the 4 edge-slots (bits 2-3 of the 16-lane group)
#pragma unroll
    for (int o = 4; o <= 8; o <<= 1) {
        denom += __shfl_xor(denom, o, 64);
        ac.x += __shfl_xor(ac.x, o, 64); ac.y += __shfl_xor(ac.y, o, 64);
        ac.z += __shfl_xor(ac.z, o, 64); ac.w += __shfl_xor(ac.w, o, 64);
    }
    if (s == 0) {
        float inv = 1.f / (denom + 1e-16f);
        float4 bi = bias4[fidx];
        float4 o;
        o.x = ac.x * inv + bi.x; o.y = ac.y * inv + bi.y;
        o.z = ac.z * inv + bi.z; o.w = ac.w * inv + bi.w;
        if (out4) out4[(size_t)i * 32 + fidx] = o;
        if (nhi) {
            short4v hv, lv;
            short hh, ll;
            split1(o.x, hh, ll); hv[0] = hh; lv[0] = ll;
            split1(o.y, hh, ll); hv[1] = hh; lv[1] = ll;
            split1(o.z, hh, ll); hv[2] = hh; lv[2] = ll;
            split1(o.w, hh, ll); hv[3] = hh; lv[3] = ll;
            *(short4v*)&nhi[(size_t)i * 128 + h * 16 + fl * 4] = hv;
            *(short4v*)&nlo[(size_t)i * 128 + h * 16 + fl * 4] = lv;
        }
    }
}

// ---------------- head ----------------

__global__ __launch_bounds__(128) void head_kernel(const float* __restrict__ x,
                                                   const float* __restrict__ w,
                                                   const float* __restrict__ bh,
                                                   const int* __restrict__ nch,
                                                   float* __restrict__ out) {
    __shared__ float r[2];
    int b = blockIdx.x, t = threadIdx.x;
    int chunk = 2 + nch[0];
    int row = (b >> 1) * chunk + (b & 1);
    float p = x[(size_t)row * 128 + t] * w[t];
#pragma unroll
    for (int o = 32; o >= 1; o >>= 1) p += __shfl_xor(p, o, 64);
    if ((t & 63) == 0) r[t >> 6] = p;
    __syncthreads();
    if (t == 0) out[b] = r[0] + r[1] + bh[0];
}

// ---------------- launch ----------------

extern "C" void kernel_launch(void* const* d_in, const int* in_sizes, int n_in,
                              void* d_out, int out_size, void* d_ws, size_t ws_size,
                              hipStream_t stream) {
    const float* x0 = (const float*)d_in[0];
    const int* ei = (const int*)d_in[1];
    const int* nchunks = (const int*)d_in[2];
    const float* Wl = (const float*)d_in[3];
    const float* bl = (const float*)d_in[4];
    const float* Wr = (const float*)d_in[5];
    const float* br = (const float*)d_in[6];
    const float* att = (const float*)d_in[7];
    const float* bias = (const float*)d_in[8];
    const float* wh = (const float*)d_in[9];
    const float* bh = (const float*)d_in[10];

    const int D = 128;
    int N = in_sizes[0] / D;   // 10000
    int E = in_sizes[1] / 2;   // 160000
    int ntiles = (N + 15) / 16;

    size_t fN = (size_t)N * D;
    float* xl = (float*)d_ws;
    float* xr = xl + fN;
    float* xout = xr + fN;
    short* cvH0 = (short*)(xout + fN);
    short* cvL0 = cvH0 + fN;
    short* cvH1 = cvL0 + fN;
    short* cvL1 = cvH1 + fN;
    short* Whi = cvL1 + fN;
    short* Wlo = Whi + 7 * (size_t)WFRAG;
    int* deg = (int*)(Wlo + 7 * (size_t)WFRAG);
    int* off = deg + N;
    int* cur = off + N + 1;
    int* esrc = cur + N;

    hipMemsetAsync(deg, 0, (size_t)N * sizeof(int), stream);
    prologue<<<112 + 640, 256, 0, stream>>>(Wl, Wr, Whi, Wlo, (const float4*)x0,
                                            cvH0, cvL0, ei, deg, N, E);
    scan_gemm0<<<257, 512, 0, stream>>>(deg, off, cur, N, cvH0, cvL0, Whi, Wlo,
                                        bl, br, xl, xr, ntiles);
    fill_kernel<<<(E + 255) / 256, 256, 0, stream>>>(ei, E, N, cur, esrc);

    // layers 0..5: head-sliced agg (xl,xr -> cv pair), then GEMM (cv -> xl,xr)
    int aggblocks = ((N + 15) / 16) * 8;   // node-blocks x 8 heads; head = blockIdx & 7
    for (int l = 0; l < 6; l++) {
        agg_sliced<<<aggblocks, 256, 0, stream>>>((const float4*)xl, (const float4*)xr,
                                                  off, esrc,
                                                  (const float4*)(att + (size_t)l * D),
                                                  (const float4*)(bias + (size_t)l * D),
                                                  cvH1, cvL1, (float4*)nullptr, N);
        gemm_x<<<256, 512, 0, stream>>>(cvH1, cvL1,
                                        Whi + (size_t)(l + 1) * WFRAG,
                                        Wlo + (size_t)(l + 1) * WFRAG,
                                        bl + (size_t)(l + 1) * D,
                                        br + (size_t)(l + 1) * D,
                                        xl, xr, N, ntiles);
    }

    // layer 6: head-sliced agg -> fp32 node features
    agg_sliced<<<aggblocks, 256, 0, stream>>>((const float4*)xl, (const float4*)xr,
                                              off, esrc,
                                              (const float4*)(att + 6 * (size_t)D),
                                              (const float4*)(bias + 6 * (size_t)D),
                                              (short*)nullptr, (short*)nullptr,
                                              (float4*)xout, N);

    head_kernel<<<out_size, 128, 0, stream>>>(xout, wh, bh, nchunks, (float*)d_out);
}